// Round 6
// baseline (182.207 us; speedup 1.0000x reference)
//
#include <hip/hip_runtime.h>
#include <hip/hip_bf16.h>

typedef __attribute__((ext_vector_type(8))) short short8;
typedef __attribute__((ext_vector_type(4))) float floatx4;
typedef __attribute__((ext_vector_type(8))) _Float16 half8;
typedef __attribute__((ext_vector_type(4))) _Float16 half4;
typedef __attribute__((ext_vector_type(2))) __fp16 fp16x2_raw;

using bf16 = __hip_bfloat16;
using fp16 = _Float16;

#define S_LEN 2048
#define DM 1024
#define NH 16
#define DH 64
#define WIN 256

// ---------- helpers ----------
__device__ __forceinline__ unsigned short f2b(float f) {
  __hip_bfloat16 h = __float2bfloat16(f);
  return *reinterpret_cast<unsigned short*>(&h);
}
__device__ __forceinline__ unsigned short f2h(float f) {
  fp16 h = (fp16)f;
  return *reinterpret_cast<unsigned short*>(&h);
}
__device__ __forceinline__ half4 pack4(float a, float b, float c, float d) {
  union { half4 h4; fp16x2_raw h2[2]; } u;
  u.h2[0] = __builtin_amdgcn_cvt_pkrtz(a, b);
  u.h2[1] = __builtin_amdgcn_cvt_pkrtz(c, d);
  return u.h4;
}
__device__ __forceinline__ void lds_load16(void* lds, const void* gptr) {
  __builtin_amdgcn_global_load_lds(
      (const __attribute__((address_space(1))) unsigned int*)gptr,
      (__attribute__((address_space(3))) unsigned int*)lds, 16, 0, 0);
}

// ---------- K1: fused prep. z<4: W[k][n] fp32 -> Wt[n][k] bf16; z==4: x fp32->bf16 ----------
__global__ __launch_bounds__(256) void k_prep(const float* __restrict__ x,
                                              const float* __restrict__ W0,
                                              const float* __restrict__ W1,
                                              const float* __restrict__ W2,
                                              const float* __restrict__ W3,
                                              bf16* __restrict__ wT,
                                              ushort4* __restrict__ xb) {
  const int tx = threadIdx.x, ty = threadIdx.y;  // block (32,8)
  if (blockIdx.z == 4) {
    const int tid = ty * 32 + tx;
    const int blk = blockIdx.y * 32 + blockIdx.x;
    const float4* in4 = (const float4*)x;
    #pragma unroll
    for (int k = 0; k < 4; ++k) {
      int i = k * 262144 + blk * 256 + tid;
      float4 v = in4[i];
      ushort4 o;
      o.x = f2b(v.x); o.y = f2b(v.y); o.z = f2b(v.z); o.w = f2b(v.w);
      xb[i] = o;
    }
    return;
  }
  __shared__ float t[32][33];
  const float* W = (blockIdx.z == 0) ? W0 : (blockIdx.z == 1) ? W1 : (blockIdx.z == 2) ? W2 : W3;
  bf16* O = wT + (size_t)blockIdx.z * 1024 * 1024;
  int x0 = blockIdx.x * 32, y0 = blockIdx.y * 32;
  #pragma unroll
  for (int i = 0; i < 32; i += 8) t[ty + i][tx] = W[(size_t)(y0 + ty + i) * 1024 + x0 + tx];
  __syncthreads();
  #pragma unroll
  for (int i = 0; i < 32; i += 8)
    O[(size_t)(x0 + ty + i) * 1024 + y0 + tx] = __float2bfloat16(t[tx][ty + i]);
}

// ---------- K2: QKV projection, 256x256 tile, 8-wave, faithful m201 8-phase template ----------
// C = A[4096][1024] * Bt[3072][1024]^T. BK=64, 16 K-tiles, 2 K-tiles/iter (u=buf0, v=buf1),
// 8 phases/iter. EXACTLY ONE 16KiB half-tile staged per phase (fine interleave), counted
// s_waitcnt vmcnt(4) only at phases 4 and 8 (2 newest stages in flight). Explicit
// lgkmcnt(0) after each raw barrier; setprio(1) around MFMA clusters.
// Region-freedom: buf regions become free 1-2 phases before their stage slot:
//   A(v)@phases 1,2 (free after prev-iter phase 7); B(u')@3,4 (free after 2);
//   A(u')@5,6 (free after 3); B(v')@7,8 (free after 6).
__global__ __launch_bounds__(512) void k_qkv(const bf16* __restrict__ A,
                                             const bf16* __restrict__ Bt,
                                             const float* __restrict__ bias_q,
                                             const float* __restrict__ bias_k,
                                             const float* __restrict__ bias_v,
                                             fp16* __restrict__ Qh, fp16* __restrict__ Kh,
                                             fp16* __restrict__ Vt) {
  __shared__ __align__(16) char lds[131072];
  const int tid = threadIdx.x;
  const int wave = tid >> 6, lane = tid & 63;
  const int ln = lane & 15, quad = lane >> 4;
  const int wr = wave >> 2, wc = wave & 3;  // 2 x 4 wave grid; per-wave 128x64 output

  const int gi = blockIdx.x;                 // 192 blocks, XCD swizzle
  const int wg = (gi & 7) * 24 + (gi >> 3);
  const int mt = wg / 12, nt = wg % 12;      // 16 M-tiles x 12 N-tiles

  auto mkF = [](int p) {
    int q = p ^ (((p >> 9) & 1) << 5);
    int sub = q >> 10;
    int w = q & 1023;
    return (((sub >> 1) << 4) + (w >> 6)) * 2048 + (sub & 1) * 64 + (w & 63);
  };
  const int F0 = mkF(tid * 16);
  const int F1 = mkF(8192 + tid * 16);
  const char* Ab = (const char*)A + (size_t)mt * 524288;   // 256 rows * 2048B
  const char* Bb = (const char*)Bt + (size_t)nt * 524288;

  auto stg = [&](int region, const char* g) {  // one 16KiB half-tile (2 loads/thread)
    lds_load16(lds + region + wave * 1024, g + F0);
    lds_load16(lds + region + 8192 + wave * 1024, g + F1);
  };

  // Buffer layout (per 64KiB buffer): A-lo(0) | A-hi(16K) | B-lo(32K) | B-hi(48K)
  // ---- prologue: tile0 all 4 halves -> buf0; tile1 B halves -> buf1 ----
  stg(32768, Bb);                     // B-lo(0)
  stg(49152, Bb + 262144);            // B-hi(0)
  stg(0,     Ab);                     // A-lo(0)
  stg(16384, Ab + 262144);            // A-hi(0)
  stg(65536 + 32768, Bb + 128);       // B-lo(1)
  stg(65536 + 49152, Bb + 262144 + 128);  // B-hi(1)

  floatx4 acc[8][4];
  #pragma unroll
  for (int i = 0; i < 8; ++i)
    #pragma unroll
    for (int j = 0; j < 4; ++j) acc[i][j] = (floatx4){0.f, 0.f, 0.f, 0.f};

  // fragment read offset: row r16=ln (64B stride in subtile), col quad*16B, swizzled
  const int lnq = ln * 64 + ((quad * 16) ^ ((ln & 8) << 2));
  const int aoff = wr * 16384 + lnq;                                  // + mi*2048 + kk*1024
  const int boff = 32768 + (wc >> 1) * 16384 + (wc & 1) * 8192 + lnq; // + ni*2048 + kk*1024

  auto RDA = [&](const char* bb, int mb, short8 (&a)[4][2]) {
    #pragma unroll
    for (int m2 = 0; m2 < 4; ++m2)
      #pragma unroll
      for (int kk = 0; kk < 2; ++kk)
        a[m2][kk] = *(const short8*)(bb + aoff + (mb + m2) * 2048 + kk * 1024);
  };
  auto RDB = [&](const char* bb, int nb, short8 (&b)[4][2]) {
    #pragma unroll
    for (int n2 = nb; n2 < nb + 2; ++n2)
      #pragma unroll
      for (int kk = 0; kk < 2; ++kk)
        b[n2][kk] = *(const short8*)(bb + boff + n2 * 2048 + kk * 1024);
  };
  auto MM = [&](int mb, int nb, short8 (&a)[4][2], short8 (&b)[4][2]) {
    __builtin_amdgcn_s_barrier();
    asm volatile("s_waitcnt lgkmcnt(0)" ::: "memory");
    __builtin_amdgcn_s_setprio(1);
    #pragma unroll
    for (int m2 = 0; m2 < 4; ++m2)
      #pragma unroll
      for (int n2 = nb; n2 < nb + 2; ++n2) {
        acc[mb + m2][n2] = __builtin_amdgcn_mfma_f32_16x16x32_bf16(a[m2][0], b[n2][0], acc[mb + m2][n2], 0, 0, 0);
        acc[mb + m2][n2] = __builtin_amdgcn_mfma_f32_16x16x32_bf16(a[m2][1], b[n2][1], acc[mb + m2][n2], 0, 0, 0);
      }
    __builtin_amdgcn_s_setprio(0);
    __builtin_amdgcn_s_barrier();
  };

  asm volatile("s_waitcnt vmcnt(4)" ::: "memory");  // tile0 landed; tile1's B in flight
  __builtin_amdgcn_s_barrier();

  for (int i = 0; i < 8; ++i) {
    const char* bu = lds;           // buf0: tile u = 2i
    const char* bv = lds + 65536;   // buf1: tile v = 2i+1
    const int o1 = (2 * i + 1) * 128, o2 = (2 * i + 2) * 128, o3 = (2 * i + 3) * 128;
    const bool pf = (i < 7);
    short8 a0[4][2], a1[4][2], b0[4][2];

    // phase 1: u reads A m0-3 + B n0-1; stage A-lo(v)
    RDA(bu, 0, a0); RDB(bu, 0, b0);
    stg(65536 + 0, Ab + o1);
    MM(0, 0, a0, b0);
    // phase 2: B n2-3; stage A-hi(v)
    RDB(bu, 2, b0);
    stg(65536 + 16384, Ab + 262144 + o1);
    MM(0, 2, a0, b0);
    // phase 3: A m4-7; stage B-lo(u')
    RDA(bu, 4, a1);
    if (pf) stg(32768, Bb + o2);
    MM(4, 0, a1, b0);
    // phase 4: stage B-hi(u'); counted vmcnt
    if (pf) {
      stg(49152, Bb + 262144 + o2);
      asm volatile("s_waitcnt vmcnt(4)" ::: "memory");
    } else {
      asm volatile("s_waitcnt vmcnt(0)" ::: "memory");
    }
    MM(4, 2, a1, b0);

    // phase 5: v reads A m0-3 + B n0-1; stage A-lo(u')
    RDA(bv, 0, a0); RDB(bv, 0, b0);
    if (pf) stg(0, Ab + o2);
    MM(0, 0, a0, b0);
    // phase 6: B n2-3; stage A-hi(u')
    RDB(bv, 2, b0);
    if (pf) stg(16384, Ab + 262144 + o2);
    MM(0, 2, a0, b0);
    // phase 7: A m4-7; stage B-lo(v')
    RDA(bv, 4, a1);
    if (pf) stg(65536 + 32768, Bb + o3);
    MM(4, 0, a1, b0);
    // phase 8: stage B-hi(v'); counted vmcnt
    if (pf) {
      stg(65536 + 49152, Bb + 262144 + o3);
      asm volatile("s_waitcnt vmcnt(4)" ::: "memory");
    } else {
      asm volatile("s_waitcnt vmcnt(0)" ::: "memory");
    }
    MM(4, 2, a1, b0);
  }

  // ---------- epilogue ----------
  const int g = nt >> 2;  // 0=Q, 1=K, 2=V (block-uniform)
  if (g == 2) {
    #pragma unroll
    for (int ni = 0; ni < 4; ++ni) {
      int nn = (nt & 3) * 256 + wc * 64 + ni * 16 + ln;
      int h = nn >> 6, dd = nn & 63;
      float bias = bias_v[nn];
      #pragma unroll
      for (int mi = 0; mi < 8; ++mi) {
        int m = mt * 256 + wr * 128 + mi * 16 + quad * 4;
        int b = m >> 11, s = m & 2047;
        ushort4 pk;
        pk.x = f2h(acc[mi][ni][0] + bias);
        pk.y = f2h(acc[mi][ni][1] + bias);
        pk.z = f2h(acc[mi][ni][2] + bias);
        pk.w = f2h(acc[mi][ni][3] + bias);
        *(ushort4*)&Vt[((size_t)((b * NH + h) * DH + dd)) * S_LEN + s] = pk;
      }
    }
  } else {
    const float* bp = (g == 0) ? bias_q : bias_k;
    fp16* og = (g == 0) ? Qh : Kh;
    #pragma unroll
    for (int ni = 0; ni < 4; ++ni) {
      int nn = (nt & 3) * 256 + wc * 64 + ni * 16 + ln;
      int h = nn >> 6, dd = nn & 63;
      float bias = bp[nn];
      #pragma unroll
      for (int mi = 0; mi < 8; ++mi) {
        #pragma unroll
        for (int r = 0; r < 4; ++r) {
          int m = mt * 256 + wr * 128 + mi * 16 + quad * 4 + r;
          int b = m >> 11, s = m & 2047;
          og[(size_t)((b * NH + h) * S_LEN + s) * DH + dd] = (fp16)(acc[mi][ni][r] + bias);
        }
      }
    }
  }
}

// ---------- K4: bf16 MFMA GEMM (output projection), 128x128 tile, unchanged ----------
template <int MODE>
__global__ __launch_bounds__(256) void k_gemm(const bf16* __restrict__ A,
                                              const bf16* __restrict__ Bt,
                                              const float* __restrict__ bias_q,
                                              const float* __restrict__ bias_k,
                                              const float* __restrict__ bias_v,
                                              fp16* __restrict__ Qh, fp16* __restrict__ Kh,
                                              fp16* __restrict__ Vt, float* __restrict__ outF) {
  __shared__ __align__(16) bf16 As[2][128 * 32];
  __shared__ __align__(16) bf16 Bs[2][128 * 32];
  const int tid = threadIdx.x;
  const int wave = tid >> 6, lane = tid & 63;
  const int gi = blockIdx.x;
  const int xcd = gi & 7, grr = gi >> 3;
  const int m0 = (xcd * 4 + (grr & 3)) * 128;
  const int n0 = (grr >> 2) * 128;
  const int r0 = tid >> 2;
  const int cb = (tid & 3) * 16;
  const char* Ag = (const char*)A + (size_t)(m0 + r0) * 2048 + cb;
  const char* Bg = (const char*)Bt + (size_t)(n0 + r0) * 2048 + cb;
  char* As0W = (char*)&As[0][0] + wave * 1024;
  char* As1W = (char*)&As[1][0] + wave * 1024;
  char* Bs0W = (char*)&Bs[0][0] + wave * 1024;
  char* Bs1W = (char*)&Bs[1][0] + wave * 1024;
  const int wm = (wave & 1) * 64, wn = (wave >> 1) * 64;
  const int ln = lane & 15, quad = lane >> 4;

  floatx4 acc[4][4];
  #pragma unroll
  for (int i = 0; i < 4; i++)
    #pragma unroll
    for (int j = 0; j < 4; j++) acc[i][j] = (floatx4){0.f, 0.f, 0.f, 0.f};

  for (int k0 = 0; k0 < 1024; k0 += 64) {
    __syncthreads();
    lds_load16(As0W,        Ag + k0 * 2);
    lds_load16(As0W + 4096, Ag + 64 * 2048 + k0 * 2);
    lds_load16(As1W,        Ag + k0 * 2 + 64);
    lds_load16(As1W + 4096, Ag + 64 * 2048 + k0 * 2 + 64);
    lds_load16(Bs0W,        Bg + k0 * 2);
    lds_load16(Bs0W + 4096, Bg + 64 * 2048 + k0 * 2);
    lds_load16(Bs1W,        Bg + k0 * 2 + 64);
    lds_load16(Bs1W + 4096, Bg + 64 * 2048 + k0 * 2 + 64);
    __syncthreads();
    short8 af0[4], af1[4], bf0[4], bf1[4];
    #pragma unroll
    for (int mi = 0; mi < 4; mi++) {
      af0[mi] = *(const short8*)&As[0][(wm + mi * 16 + ln) * 32 + quad * 8];
      af1[mi] = *(const short8*)&As[1][(wm + mi * 16 + ln) * 32 + quad * 8];
    }
    #pragma unroll
    for (int ni = 0; ni < 4; ni++) {
      bf0[ni] = *(const short8*)&Bs[0][(wn + ni * 16 + ln) * 32 + quad * 8];
      bf1[ni] = *(const short8*)&Bs[1][(wn + ni * 16 + ln) * 32 + quad * 8];
    }
    #pragma unroll
    for (int mi = 0; mi < 4; mi++)
      #pragma unroll
      for (int ni = 0; ni < 4; ni++) {
        acc[mi][ni] = __builtin_amdgcn_mfma_f32_16x16x32_bf16(af0[mi], bf0[ni], acc[mi][ni], 0, 0, 0);
        acc[mi][ni] = __builtin_amdgcn_mfma_f32_16x16x32_bf16(af1[mi], bf1[ni], acc[mi][ni], 0, 0, 0);
      }
  }

  if constexpr (MODE == 0) {
    #pragma unroll
    for (int ni = 0; ni < 4; ni++) {
      int n = n0 + wn + ni * 16 + ln;
      int g = n >> 10, nn = n & 1023;
      int h = nn >> 6, dd = nn & 63;
      if (g == 2) {
        float bias = bias_v[nn];
        #pragma unroll
        for (int mi = 0; mi < 4; mi++) {
          int m = m0 + wm + mi * 16 + quad * 4;
          int b = m >> 11, s = m & 2047;
          ushort4 pk;
          pk.x = f2h(acc[mi][ni][0] + bias);
          pk.y = f2h(acc[mi][ni][1] + bias);
          pk.z = f2h(acc[mi][ni][2] + bias);
          pk.w = f2h(acc[mi][ni][3] + bias);
          *(ushort4*)&Vt[((size_t)(b * NH + h) * DH + dd) * S_LEN + s] = pk;
        }
      } else {
        const float* bp = (g == 0) ? bias_q : bias_k;
        fp16* og = (g == 0) ? Qh : Kh;
        float bias = bp[nn];
        #pragma unroll
        for (int mi = 0; mi < 4; mi++) {
          #pragma unroll
          for (int r = 0; r < 4; r++) {
            int m = m0 + wm + mi * 16 + quad * 4 + r;
            int b = m >> 11, s = m & 2047;
            og[(size_t)((b * NH + h) * S_LEN + s) * DH + dd] = (fp16)(acc[mi][ni][r] + bias);
          }
        }
      }
    }
  } else {
    #pragma unroll
    for (int ni = 0; ni < 4; ni++) {
      int n = n0 + wn + ni * 16 + ln;
      float bias = bias_q[n];
      #pragma unroll
      for (int mi = 0; mi < 4; mi++)
        #pragma unroll
        for (int r = 0; r < 4; r++) {
          int m = m0 + wm + mi * 16 + quad * 4 + r;
          outF[(size_t)m * 1024 + n] = acc[mi][ni][r] + bias;
        }
    }
  }
}

// ---------- K3: flash attention, 8 waves / 128 q-rows per block, 512 blocks (unchanged) ----------
__global__ __launch_bounds__(512, 4) void k_attn(const fp16* __restrict__ Qh,
                                                 const fp16* __restrict__ Kh,
                                                 const fp16* __restrict__ Vt,
                                                 bf16* __restrict__ aout) {
  __shared__ __align__(16) fp16 KsL[2][64 * 72];
  __shared__ __align__(16) fp16 VsL[2][64 * 72];

  const int i = blockIdx.x;
  const int xcd = i & 7, rr = i >> 3;      // rr in [0,64)
  const int bh = xcd * 4 + (rr & 3);
  const int tile = rr >> 2;                // [0,16), 128 q-rows each
  const int b = bh >> 4, h = bh & 15;
  const size_t base = (size_t)bh * S_LEN * DH;
  const fp16* Qp = Qh + base;
  const fp16* Kp = Kh + base;
  const fp16* Vp = Vt + base;  // [d][s]
  const float SC2 = 0.18033688011112042f;  // 0.125 * log2(e)
  const int tid = threadIdx.x;

  const int w = tid >> 6, lane = tid & 63;
  const int ln = lane & 15, quad = lane >> 4;
  const int qb = tile * 128;
  const int qw = qb + w * 16;

  const half8 bq0 = *(const half8*)(Qp + (size_t)(qw + ln) * DH + quad * 8);
  const half8 bq1 = *(const half8*)(Qp + (size_t)(qw + ln) * DH + 32 + quad * 8);

  floatx4 acc[4];  // O^T tiles: d = dt*16+quad*4+r, col q = ln
  float l_i;

  // ---- init: fold global key j=0 ----
  {
    const half8 k0a = *(const half8*)(Kp + quad * 8);
    const half8 k0b = *(const half8*)(Kp + 32 + quad * 8);
    float s0 = 0.f;
    #pragma unroll
    for (int e = 0; e < 8; ++e)
      s0 += (float)bq0[e] * (float)k0a[e] + (float)bq1[e] * (float)k0b[e];
    s0 += __shfl_xor(s0, 16, 64);
    s0 += __shfl_xor(s0, 32, 64);
    float p0 = exp2f(fmaf(s0, SC2, -8.f));
    l_i = (quad == 0) ? p0 : 0.f;  // count j=0 once per q row
    #pragma unroll
    for (int dt = 0; dt < 4; ++dt)
      #pragma unroll
      for (int r = 0; r < 4; ++r)
        acc[dt][r] = p0 * (float)Vp[(size_t)(dt * 16 + quad * 4 + r) * S_LEN];
  }

  // ---- block-uniform chunk range for 128 q-rows ----
  int cs = qb - WIN; if (cs < 0) cs = 0;
  int ce = qb + 128 + WIN; if (ce > S_LEN) ce = S_LEN;

  // ---- staging: 512 threads, one uint4 each for K and V per chunk ----
  const int rs = tid >> 3, cls = (tid & 7) * 8;

  uint4 kreg, vreg;
  auto stage_load = [&](int c) {
    kreg = *(const uint4*)(Kp + (size_t)(c + rs) * DH + cls);
    vreg = *(const uint4*)(Vp + (size_t)rs * S_LEN + c + cls);
  };
  auto stage_write = [&](int buf) {
    *(uint4*)&KsL[buf][rs * 72 + cls] = kreg;
    *(uint4*)&VsL[buf][rs * 72 + cls] = vreg;
  };

  auto compute = [&](int c, int buf) {
    floatx4 s[4];
    #pragma unroll
    for (int jt = 0; jt < 4; ++jt) {
      half8 k0 = *(const half8*)&KsL[buf][(jt * 16 + ln) * 72 + quad * 8];
      half8 k1 = *(const half8*)&KsL[buf][(jt * 16 + ln) * 72 + 32 + quad * 8];
      floatx4 z = (floatx4){0.f, 0.f, 0.f, 0.f};
      z = __builtin_amdgcn_mfma_f32_16x16x32_f16(k0, bq0, z, 0, 0, 0);
      s[jt] = __builtin_amdgcn_mfma_f32_16x16x32_f16(k1, bq1, z, 0, 0, 0);
    }
    half4 v01[8];
    #pragma unroll
    for (int dt = 0; dt < 2; ++dt)
      #pragma unroll
      for (int jt = 0; jt < 4; ++jt)
        v01[dt * 4 + jt] =
            *(const half4*)&VsL[buf][(dt * 16 + ln) * 72 + jt * 16 + quad * 4];
    const bool full_in = (c != 0) && (c >= qw - 241) && (c <= qw + 193);
    half4 Pt[4];
    if (full_in) {
      #pragma unroll
      for (int jt = 0; jt < 4; ++jt) {
        float p0 = exp2f(fmaf(s[jt][0], SC2, -8.f));
        float p1 = exp2f(fmaf(s[jt][1], SC2, -8.f));
        float p2 = exp2f(fmaf(s[jt][2], SC2, -8.f));
        float p3 = exp2f(fmaf(s[jt][3], SC2, -8.f));
        Pt[jt] = pack4(p0, p1, p2, p3);
        l_i += (p0 + p1) + (p2 + p3);
      }
    } else {
      const int q = qw + ln;
      #pragma unroll
      for (int jt = 0; jt < 4; ++jt) {
        float pv[4];
        #pragma unroll
        for (int r = 0; r < 4; ++r) {
          int j = c + jt * 16 + quad * 4 + r;
          int dq = q - j;
          bool ok = (dq <= WIN && dq >= -WIN) && (j != 0);
          pv[r] = ok ? exp2f(fmaf(s[jt][r], SC2, -8.f)) : 0.f;
        }
        Pt[jt] = pack4(pv[0], pv[1], pv[2], pv[3]);
        l_i += (pv[0] + pv[1]) + (pv[2] + pv[3]);
      }
    }
    half4 v23[8];
    #pragma unroll
    for (int dt = 0; dt < 2; ++dt)
      #pragma unroll
      for (int jt = 0; jt < 4; ++jt)
        v23[dt * 4 + jt] =
            *(const half4*)&VsL[buf][((dt + 2) * 16 + ln) * 72 + jt * 16 + quad * 4];
    #pragma unroll
    for (int jt = 0; jt < 4; ++jt) {
      acc[0] = __builtin_amdgcn_mfma_f32_16x16x16f16(v01[jt], Pt[jt], acc[0], 0, 0, 0);
      acc[1] = __builtin_amdgcn_mfma_f32_16x16x16f16(v01[4 + jt], Pt[jt], acc[1], 0, 0, 0);
    }
    #pragma unroll
    for (int jt = 0; jt < 4; ++jt) {
      acc[2] = __builtin_amdgcn_mfma_f32_16x16x16f16(v23[jt], Pt[jt], acc[2], 0, 0, 0);
      acc[3] = __builtin_amdgcn_mfma_f32_16x16x16f16(v23[4 + jt], Pt[jt], acc[3], 0, 0, 0);
    }
  };

  stage_load(cs);
  stage_write(0);
  __syncthreads();
  int buf = 0;
  for (int c = cs; c < ce; c += 64) {
    const bool hasnext = (c + 64 < ce);
    if (hasnext) stage_load(c + 64);
    compute(c, buf);
    if (hasnext) stage_write(buf ^ 1);
    __syncthreads();
    buf ^= 1;
  }

  // ---- window epilogue ----
  {
    float lt = l_i;
    lt += __shfl_xor(lt, 16, 64);
    lt += __shfl_xor(lt, 32, 64);
    const float inv = 1.0f / lt;
    const int q = qw + ln;
    if (q != 0) {
      #pragma unroll
      for (int dt = 0; dt < 4; ++dt) {
        ushort4 pk;
        pk.x = f2b(acc[dt][0] * inv);
        pk.y = f2b(acc[dt][1] * inv);
        pk.z = f2b(acc[dt][2] * inv);
        pk.w = f2b(acc[dt][3] * inv);
        *(ushort4*)&aout[(size_t)(b * S_LEN + q) * DM + h * DH + dt * 16 + quad * 4] = pk;
      }
    }
  }

  // ---- global q=0 row: handled by tile==0 blocks ----
  if (tile == 0) {
    float* sP = (float*)&KsL[0][0];   // 2048 floats = 8KB
    float* oR = (float*)&VsL[0][0];   // 512 floats
    float* red = (float*)&VsL[1][0];  // 8 floats
    const int g2 = lane >> 3, e8 = lane & 7;
    const half8 q0t = *(const half8*)(Qp + e8 * 8);
    float lsum = 0.f;
    for (int it = 0; it < 32; ++it) {
      int grp = w * 32 + it;  // key j = grp*8 + g2
      const half8 kv = *(const half8*)(Kp + (size_t)(grp * 8 + g2) * DH + e8 * 8);
      float p = 0.f;
      #pragma unroll
      for (int e = 0; e < 8; ++e) p += (float)q0t[e] * (float)kv[e];
      p += __shfl_xor(p, 1, 64);
      p += __shfl_xor(p, 2, 64);
      p += __shfl_xor(p, 4, 64);
      p = exp2f(fmaf(p, SC2, -8.f));
      if (e8 == 0) sP[grp * 8 + g2] = p;
      lsum += p;  // 8x duplicated per group; divide later
    }
    #pragma unroll
    for (int off = 1; off < 64; off <<= 1) lsum += __shfl_xor(lsum, off, 64);
    if (lane == 0) red[w] = lsum;
    __syncthreads();
    const float ltot = (red[0] + red[1] + red[2] + red[3] +
                        red[4] + red[5] + red[6] + red[7]) * 0.125f;
    const int d = tid & 63, qu = tid >> 6;
    float o = 0.f;
    for (int j0 = qu * 256; j0 < qu * 256 + 256; j0 += 8) {
      half8 vv = *(const half8*)(Vp + (size_t)d * S_LEN + j0);
      #pragma unroll
      for (int e = 0; e < 8; ++e) o += sP[j0 + e] * (float)vv[e];
    }
    oR[tid] = o;
    __syncthreads();
    if (tid < 64) {
      float oo = oR[tid] + oR[tid + 64] + oR[tid + 128] + oR[tid + 192] +
                 oR[tid + 256] + oR[tid + 320] + oR[tid + 384] + oR[tid + 448];
      aout[(size_t)(b * S_LEN) * DM + h * DH + tid] = __float2bfloat16(oo / ltot);
    }
  }
}

// ---------- launch ----------
extern "C" void kernel_launch(void* const* d_in, const int* in_sizes, int n_in,
                              void* d_out, int out_size, void* d_ws, size_t ws_size,
                              hipStream_t stream) {
  const float* x  = (const float*)d_in[0];
  const float* Wq = (const float*)d_in[1];
  const float* bq = (const float*)d_in[2];
  const float* Wk = (const float*)d_in[3];
  const float* bk = (const float*)d_in[4];
  const float* Wv = (const float*)d_in[5];
  const float* bv = (const float*)d_in[6];
  const float* Wo = (const float*)d_in[7];
  const float* bo = (const float*)d_in[8];
  float* out = (float*)d_out;

  const size_t SEG = (size_t)4096 * 1024;
  bf16* xb = (bf16*)d_ws;
  bf16* wT = xb + SEG;
  fp16* Qh = (fp16*)(wT + SEG);
  fp16* Kh = Qh + SEG;
  fp16* Vt = Kh + SEG;   // [bh][d][s]
  bf16* ao = (bf16*)(Vt + SEG);

  k_prep<<<dim3(32, 32, 5), dim3(32, 8), 0, stream>>>(x, Wq, Wk, Wv, Wo, wT, (ushort4*)xb);
  k_qkv<<<dim3(192), dim3(512), 0, stream>>>(xb, wT, bq, bk, bv, Qh, Kh, Vt);
  k_attn<<<dim3(512), dim3(512), 0, stream>>>(Qh, Kh, Vt, ao);
  k_gemm<1><<<dim3(256), dim3(256), 0, stream>>>(ao, wT + (size_t)3 * 1024 * 1024, bo,
                                                 nullptr, nullptr, nullptr, nullptr, nullptr, out);
}

// Round 7
// 177.730 us; speedup vs baseline: 1.0252x; 1.0252x over previous
//
#include <hip/hip_runtime.h>
#include <hip/hip_bf16.h>

typedef __attribute__((ext_vector_type(8))) short short8;
typedef __attribute__((ext_vector_type(4))) float floatx4;
typedef __attribute__((ext_vector_type(8))) _Float16 half8;
typedef __attribute__((ext_vector_type(4))) _Float16 half4;
typedef __attribute__((ext_vector_type(2))) __fp16 fp16x2_raw;

using bf16 = __hip_bfloat16;
using fp16 = _Float16;

#define S_LEN 2048
#define DM 1024
#define NH 16
#define DH 64
#define WIN 256

// ---------- helpers ----------
__device__ __forceinline__ unsigned short f2b(float f) {
  __hip_bfloat16 h = __float2bfloat16(f);
  return *reinterpret_cast<unsigned short*>(&h);
}
__device__ __forceinline__ unsigned short f2h(float f) {
  fp16 h = (fp16)f;
  return *reinterpret_cast<unsigned short*>(&h);
}
__device__ __forceinline__ half4 pack4(float a, float b, float c, float d) {
  union { half4 h4; fp16x2_raw h2[2]; } u;
  u.h2[0] = __builtin_amdgcn_cvt_pkrtz(a, b);
  u.h2[1] = __builtin_amdgcn_cvt_pkrtz(c, d);
  return u.h4;
}
__device__ __forceinline__ void lds_load16(void* lds, const void* gptr) {
  __builtin_amdgcn_global_load_lds(
      (const __attribute__((address_space(1))) unsigned int*)gptr,
      (__attribute__((address_space(3))) unsigned int*)lds, 16, 0, 0);
}

// ---------- K1: fused prep. z<4: W[k][n] fp32 -> Wt[n][k] bf16; z==4: x fp32->bf16 ----------
__global__ __launch_bounds__(256) void k_prep(const float* __restrict__ x,
                                              const float* __restrict__ W0,
                                              const float* __restrict__ W1,
                                              const float* __restrict__ W2,
                                              const float* __restrict__ W3,
                                              bf16* __restrict__ wT,
                                              ushort4* __restrict__ xb) {
  const int tx = threadIdx.x, ty = threadIdx.y;  // block (32,8)
  if (blockIdx.z == 4) {
    const int tid = ty * 32 + tx;
    const int blk = blockIdx.y * 32 + blockIdx.x;
    const float4* in4 = (const float4*)x;
    #pragma unroll
    for (int k = 0; k < 4; ++k) {
      int i = k * 262144 + blk * 256 + tid;
      float4 v = in4[i];
      ushort4 o;
      o.x = f2b(v.x); o.y = f2b(v.y); o.z = f2b(v.z); o.w = f2b(v.w);
      xb[i] = o;
    }
    return;
  }
  __shared__ float t[32][33];
  const float* W = (blockIdx.z == 0) ? W0 : (blockIdx.z == 1) ? W1 : (blockIdx.z == 2) ? W2 : W3;
  bf16* O = wT + (size_t)blockIdx.z * 1024 * 1024;
  int x0 = blockIdx.x * 32, y0 = blockIdx.y * 32;
  #pragma unroll
  for (int i = 0; i < 32; i += 8) t[ty + i][tx] = W[(size_t)(y0 + ty + i) * 1024 + x0 + tx];
  __syncthreads();
  #pragma unroll
  for (int i = 0; i < 32; i += 8)
    O[(size_t)(x0 + ty + i) * 1024 + y0 + tx] = __float2bfloat16(t[tx][ty + i]);
}

// ---------- K2: QKV projection, 256x256 tile, 8-wave, m201 8-phase template (unchanged) ----------
__global__ __launch_bounds__(512) void k_qkv(const bf16* __restrict__ A,
                                             const bf16* __restrict__ Bt,
                                             const float* __restrict__ bias_q,
                                             const float* __restrict__ bias_k,
                                             const float* __restrict__ bias_v,
                                             fp16* __restrict__ Qh, fp16* __restrict__ Kh,
                                             fp16* __restrict__ Vt) {
  __shared__ __align__(16) char lds[131072];
  const int tid = threadIdx.x;
  const int wave = tid >> 6, lane = tid & 63;
  const int ln = lane & 15, quad = lane >> 4;
  const int wr = wave >> 2, wc = wave & 3;  // 2 x 4 wave grid; per-wave 128x64 output

  const int gi = blockIdx.x;                 // 192 blocks, XCD swizzle
  const int wg = (gi & 7) * 24 + (gi >> 3);
  const int mt = wg / 12, nt = wg % 12;      // 16 M-tiles x 12 N-tiles

  auto mkF = [](int p) {
    int q = p ^ (((p >> 9) & 1) << 5);
    int sub = q >> 10;
    int w = q & 1023;
    return (((sub >> 1) << 4) + (w >> 6)) * 2048 + (sub & 1) * 64 + (w & 63);
  };
  const int F0 = mkF(tid * 16);
  const int F1 = mkF(8192 + tid * 16);
  const char* Ab = (const char*)A + (size_t)mt * 524288;   // 256 rows * 2048B
  const char* Bb = (const char*)Bt + (size_t)nt * 524288;

  auto stg = [&](int region, const char* g) {  // one 16KiB half-tile (2 loads/thread)
    lds_load16(lds + region + wave * 1024, g + F0);
    lds_load16(lds + region + 8192 + wave * 1024, g + F1);
  };

  // Buffer layout (per 64KiB buffer): A-lo(0) | A-hi(16K) | B-lo(32K) | B-hi(48K)
  stg(32768, Bb);                     // B-lo(0)
  stg(49152, Bb + 262144);            // B-hi(0)
  stg(0,     Ab);                     // A-lo(0)
  stg(16384, Ab + 262144);            // A-hi(0)
  stg(65536 + 32768, Bb + 128);       // B-lo(1)
  stg(65536 + 49152, Bb + 262144 + 128);  // B-hi(1)

  floatx4 acc[8][4];
  #pragma unroll
  for (int i = 0; i < 8; ++i)
    #pragma unroll
    for (int j = 0; j < 4; ++j) acc[i][j] = (floatx4){0.f, 0.f, 0.f, 0.f};

  const int lnq = ln * 64 + ((quad * 16) ^ ((ln & 8) << 2));
  const int aoff = wr * 16384 + lnq;                                  // + mi*2048 + kk*1024
  const int boff = 32768 + (wc >> 1) * 16384 + (wc & 1) * 8192 + lnq; // + ni*2048 + kk*1024

  auto RDA = [&](const char* bb, int mb, short8 (&a)[4][2]) {
    #pragma unroll
    for (int m2 = 0; m2 < 4; ++m2)
      #pragma unroll
      for (int kk = 0; kk < 2; ++kk)
        a[m2][kk] = *(const short8*)(bb + aoff + (mb + m2) * 2048 + kk * 1024);
  };
  auto RDB = [&](const char* bb, int nb, short8 (&b)[4][2]) {
    #pragma unroll
    for (int n2 = nb; n2 < nb + 2; ++n2)
      #pragma unroll
      for (int kk = 0; kk < 2; ++kk)
        b[n2][kk] = *(const short8*)(bb + boff + n2 * 2048 + kk * 1024);
  };
  auto MM = [&](int mb, int nb, short8 (&a)[4][2], short8 (&b)[4][2]) {
    __builtin_amdgcn_s_barrier();
    asm volatile("s_waitcnt lgkmcnt(0)" ::: "memory");
    __builtin_amdgcn_s_setprio(1);
    #pragma unroll
    for (int m2 = 0; m2 < 4; ++m2)
      #pragma unroll
      for (int n2 = nb; n2 < nb + 2; ++n2) {
        acc[mb + m2][n2] = __builtin_amdgcn_mfma_f32_16x16x32_bf16(a[m2][0], b[n2][0], acc[mb + m2][n2], 0, 0, 0);
        acc[mb + m2][n2] = __builtin_amdgcn_mfma_f32_16x16x32_bf16(a[m2][1], b[n2][1], acc[mb + m2][n2], 0, 0, 0);
      }
    __builtin_amdgcn_s_setprio(0);
    __builtin_amdgcn_s_barrier();
  };

  asm volatile("s_waitcnt vmcnt(4)" ::: "memory");
  __builtin_amdgcn_s_barrier();

  for (int i = 0; i < 8; ++i) {
    const char* bu = lds;           // buf0: tile u = 2i
    const char* bv = lds + 65536;   // buf1: tile v = 2i+1
    const int o1 = (2 * i + 1) * 128, o2 = (2 * i + 2) * 128, o3 = (2 * i + 3) * 128;
    const bool pf = (i < 7);
    short8 a0[4][2], a1[4][2], b0[4][2];

    // phase 1: u reads A m0-3 + B n0-1; stage A-lo(v)
    RDA(bu, 0, a0); RDB(bu, 0, b0);
    stg(65536 + 0, Ab + o1);
    MM(0, 0, a0, b0);
    // phase 2: B n2-3; stage A-hi(v)
    RDB(bu, 2, b0);
    stg(65536 + 16384, Ab + 262144 + o1);
    MM(0, 2, a0, b0);
    // phase 3: A m4-7; stage B-lo(u')
    RDA(bu, 4, a1);
    if (pf) stg(32768, Bb + o2);
    MM(4, 0, a1, b0);
    // phase 4: stage B-hi(u'); counted vmcnt
    if (pf) {
      stg(49152, Bb + 262144 + o2);
      asm volatile("s_waitcnt vmcnt(4)" ::: "memory");
    } else {
      asm volatile("s_waitcnt vmcnt(0)" ::: "memory");
    }
    MM(4, 2, a1, b0);

    // phase 5: v reads A m0-3 + B n0-1; stage A-lo(u')
    RDA(bv, 0, a0); RDB(bv, 0, b0);
    if (pf) stg(0, Ab + o2);
    MM(0, 0, a0, b0);
    // phase 6: B n2-3; stage A-hi(u')
    RDB(bv, 2, b0);
    if (pf) stg(16384, Ab + 262144 + o2);
    MM(0, 2, a0, b0);
    // phase 7: A m4-7; stage B-lo(v')
    RDA(bv, 4, a1);
    if (pf) stg(65536 + 32768, Bb + o3);
    MM(4, 0, a1, b0);
    // phase 8: stage B-hi(v'); counted vmcnt
    if (pf) {
      stg(65536 + 49152, Bb + 262144 + o3);
      asm volatile("s_waitcnt vmcnt(4)" ::: "memory");
    } else {
      asm volatile("s_waitcnt vmcnt(0)" ::: "memory");
    }
    MM(4, 2, a1, b0);
  }

  // ---------- epilogue ----------
  const int g = nt >> 2;  // 0=Q, 1=K, 2=V (block-uniform)
  if (g == 2) {
    #pragma unroll
    for (int ni = 0; ni < 4; ++ni) {
      int nn = (nt & 3) * 256 + wc * 64 + ni * 16 + ln;
      int h = nn >> 6, dd = nn & 63;
      float bias = bias_v[nn];
      #pragma unroll
      for (int mi = 0; mi < 8; ++mi) {
        int m = mt * 256 + wr * 128 + mi * 16 + quad * 4;
        int b = m >> 11, s = m & 2047;
        ushort4 pk;
        pk.x = f2h(acc[mi][ni][0] + bias);
        pk.y = f2h(acc[mi][ni][1] + bias);
        pk.z = f2h(acc[mi][ni][2] + bias);
        pk.w = f2h(acc[mi][ni][3] + bias);
        *(ushort4*)&Vt[((size_t)((b * NH + h) * DH + dd)) * S_LEN + s] = pk;
      }
    }
  } else {
    const float* bp = (g == 0) ? bias_q : bias_k;
    fp16* og = (g == 0) ? Qh : Kh;
    #pragma unroll
    for (int ni = 0; ni < 4; ++ni) {
      int nn = (nt & 3) * 256 + wc * 64 + ni * 16 + ln;
      int h = nn >> 6, dd = nn & 63;
      float bias = bp[nn];
      #pragma unroll
      for (int mi = 0; mi < 8; ++mi) {
        #pragma unroll
        for (int r = 0; r < 4; ++r) {
          int m = mt * 256 + wr * 128 + mi * 16 + quad * 4 + r;
          int b = m >> 11, s = m & 2047;
          og[(size_t)((b * NH + h) * S_LEN + s) * DH + dd] = (fp16)(acc[mi][ni][r] + bias);
        }
      }
    }
  }
}

// ---------- K4: bf16 MFMA GEMM (output projection), 128x128 tile, unchanged ----------
template <int MODE>
__global__ __launch_bounds__(256) void k_gemm(const bf16* __restrict__ A,
                                              const bf16* __restrict__ Bt,
                                              const float* __restrict__ bias_q,
                                              const float* __restrict__ bias_k,
                                              const float* __restrict__ bias_v,
                                              fp16* __restrict__ Qh, fp16* __restrict__ Kh,
                                              fp16* __restrict__ Vt, float* __restrict__ outF) {
  __shared__ __align__(16) bf16 As[2][128 * 32];
  __shared__ __align__(16) bf16 Bs[2][128 * 32];
  const int tid = threadIdx.x;
  const int wave = tid >> 6, lane = tid & 63;
  const int gi = blockIdx.x;
  const int xcd = gi & 7, grr = gi >> 3;
  const int m0 = (xcd * 4 + (grr & 3)) * 128;
  const int n0 = (grr >> 2) * 128;
  const int r0 = tid >> 2;
  const int cb = (tid & 3) * 16;
  const char* Ag = (const char*)A + (size_t)(m0 + r0) * 2048 + cb;
  const char* Bg = (const char*)Bt + (size_t)(n0 + r0) * 2048 + cb;
  char* As0W = (char*)&As[0][0] + wave * 1024;
  char* As1W = (char*)&As[1][0] + wave * 1024;
  char* Bs0W = (char*)&Bs[0][0] + wave * 1024;
  char* Bs1W = (char*)&Bs[1][0] + wave * 1024;
  const int wm = (wave & 1) * 64, wn = (wave >> 1) * 64;
  const int ln = lane & 15, quad = lane >> 4;

  floatx4 acc[4][4];
  #pragma unroll
  for (int i = 0; i < 4; i++)
    #pragma unroll
    for (int j = 0; j < 4; j++) acc[i][j] = (floatx4){0.f, 0.f, 0.f, 0.f};

  for (int k0 = 0; k0 < 1024; k0 += 64) {
    __syncthreads();
    lds_load16(As0W,        Ag + k0 * 2);
    lds_load16(As0W + 4096, Ag + 64 * 2048 + k0 * 2);
    lds_load16(As1W,        Ag + k0 * 2 + 64);
    lds_load16(As1W + 4096, Ag + 64 * 2048 + k0 * 2 + 64);
    lds_load16(Bs0W,        Bg + k0 * 2);
    lds_load16(Bs0W + 4096, Bg + 64 * 2048 + k0 * 2);
    lds_load16(Bs1W,        Bg + k0 * 2 + 64);
    lds_load16(Bs1W + 4096, Bg + 64 * 2048 + k0 * 2 + 64);
    __syncthreads();
    short8 af0[4], af1[4], bf0[4], bf1[4];
    #pragma unroll
    for (int mi = 0; mi < 4; mi++) {
      af0[mi] = *(const short8*)&As[0][(wm + mi * 16 + ln) * 32 + quad * 8];
      af1[mi] = *(const short8*)&As[1][(wm + mi * 16 + ln) * 32 + quad * 8];
    }
    #pragma unroll
    for (int ni = 0; ni < 4; ni++) {
      bf0[ni] = *(const short8*)&Bs[0][(wn + ni * 16 + ln) * 32 + quad * 8];
      bf1[ni] = *(const short8*)&Bs[1][(wn + ni * 16 + ln) * 32 + quad * 8];
    }
    #pragma unroll
    for (int mi = 0; mi < 4; mi++)
      #pragma unroll
      for (int ni = 0; ni < 4; ni++) {
        acc[mi][ni] = __builtin_amdgcn_mfma_f32_16x16x32_bf16(af0[mi], bf0[ni], acc[mi][ni], 0, 0, 0);
        acc[mi][ni] = __builtin_amdgcn_mfma_f32_16x16x32_bf16(af1[mi], bf1[ni], acc[mi][ni], 0, 0, 0);
      }
  }

  if constexpr (MODE == 0) {
    #pragma unroll
    for (int ni = 0; ni < 4; ni++) {
      int n = n0 + wn + ni * 16 + ln;
      int g = n >> 10, nn = n & 1023;
      int h = nn >> 6, dd = nn & 63;
      if (g == 2) {
        float bias = bias_v[nn];
        #pragma unroll
        for (int mi = 0; mi < 4; mi++) {
          int m = m0 + wm + mi * 16 + quad * 4;
          int b = m >> 11, s = m & 2047;
          ushort4 pk;
          pk.x = f2h(acc[mi][ni][0] + bias);
          pk.y = f2h(acc[mi][ni][1] + bias);
          pk.z = f2h(acc[mi][ni][2] + bias);
          pk.w = f2h(acc[mi][ni][3] + bias);
          *(ushort4*)&Vt[((size_t)(b * NH + h) * DH + dd) * S_LEN + s] = pk;
        }
      } else {
        const float* bp = (g == 0) ? bias_q : bias_k;
        fp16* og = (g == 0) ? Qh : Kh;
        float bias = bp[nn];
        #pragma unroll
        for (int mi = 0; mi < 4; mi++) {
          #pragma unroll
          for (int r = 0; r < 4; r++) {
            int m = m0 + wm + mi * 16 + quad * 4 + r;
            int b = m >> 11, s = m & 2047;
            og[(size_t)((b * NH + h) * S_LEN + s) * DH + dd] = (fp16)(acc[mi][ni][r] + bias);
          }
        }
      }
    }
  } else {
    #pragma unroll
    for (int ni = 0; ni < 4; ni++) {
      int n = n0 + wn + ni * 16 + ln;
      float bias = bias_q[n];
      #pragma unroll
      for (int mi = 0; mi < 4; mi++)
        #pragma unroll
        for (int r = 0; r < 4; r++) {
          int m = m0 + wm + mi * 16 + quad * 4 + r;
          outF[(size_t)m * 1024 + n] = acc[mi][ni][r] + bias;
        }
    }
  }
}

// ---------- K3: flash attention, 8 waves / 128 q-rows, 512 blocks ----------
// LDS layout change only: K/V tiles stored at stride 64 fp16 (128 B) with XOR swizzle.
// 16B slot s at row r lives at byte r*128 + ((s ^ (r&7))<<4). V additionally swaps its
// two 8B halves when (r&8) so half4 reads can XOR bit-3 with (ln&8) — kills the
// remaining 2-lane row-fold conflict. Write and read sides apply the same permutation.
__global__ __launch_bounds__(512, 4) void k_attn(const fp16* __restrict__ Qh,
                                                 const fp16* __restrict__ Kh,
                                                 const fp16* __restrict__ Vt,
                                                 bf16* __restrict__ aout) {
  __shared__ __align__(16) char KsB[16384];  // [2 bufs][64 rows][128 B]
  __shared__ __align__(16) char VsB[16384];

  const int i = blockIdx.x;
  const int xcd = i & 7, rr = i >> 3;      // rr in [0,64)
  const int bh = xcd * 4 + (rr & 3);
  const int tile = rr >> 2;                // [0,16), 128 q-rows each
  const int b = bh >> 4, h = bh & 15;
  const size_t base = (size_t)bh * S_LEN * DH;
  const fp16* Qp = Qh + base;
  const fp16* Kp = Kh + base;
  const fp16* Vp = Vt + base;  // [d][s]
  const float SC2 = 0.18033688011112042f;  // 0.125 * log2(e)
  const int tid = threadIdx.x;

  const int w = tid >> 6, lane = tid & 63;
  const int ln = lane & 15, quad = lane >> 4;
  const int r7 = ln & 7;
  const int qb = tile * 128;
  const int qw = qb + w * 16;

  const half8 bq0 = *(const half8*)(Qp + (size_t)(qw + ln) * DH + quad * 8);
  const half8 bq1 = *(const half8*)(Qp + (size_t)(qw + ln) * DH + 32 + quad * 8);

  floatx4 acc[4];  // O^T tiles: d = dt*16+quad*4+r, col q = ln
  float l_i;

  // ---- init: fold global key j=0 ----
  {
    const half8 k0a = *(const half8*)(Kp + quad * 8);
    const half8 k0b = *(const half8*)(Kp + 32 + quad * 8);
    float s0 = 0.f;
    #pragma unroll
    for (int e = 0; e < 8; ++e)
      s0 += (float)bq0[e] * (float)k0a[e] + (float)bq1[e] * (float)k0b[e];
    s0 += __shfl_xor(s0, 16, 64);
    s0 += __shfl_xor(s0, 32, 64);
    float p0 = exp2f(fmaf(s0, SC2, -8.f));
    l_i = (quad == 0) ? p0 : 0.f;  // count j=0 once per q row
    #pragma unroll
    for (int dt = 0; dt < 4; ++dt)
      #pragma unroll
      for (int r = 0; r < 4; ++r)
        acc[dt][r] = p0 * (float)Vp[(size_t)(dt * 16 + quad * 4 + r) * S_LEN];
  }

  // ---- block-uniform chunk range for 128 q-rows ----
  int cs = qb - WIN; if (cs < 0) cs = 0;
  int ce = qb + 128 + WIN; if (ce > S_LEN) ce = S_LEN;

  // ---- staging: 512 threads, one uint4 each for K and V per chunk ----
  const int rs = tid >> 3, c8 = tid & 7;
  const int wswz = rs * 128 + ((c8 ^ (rs & 7)) << 4);  // swizzled 16B slot

  uint4 kreg, vreg;
  auto stage_load = [&](int c) {
    kreg = *(const uint4*)(Kp + (size_t)(c + rs) * DH + c8 * 8);
    vreg = *(const uint4*)(Vp + (size_t)rs * S_LEN + c + c8 * 8);
  };
  auto stage_write = [&](int buf) {
    *(uint4*)(KsB + buf * 8192 + wswz) = kreg;
    uint4 vv = vreg;
    if (rs & 8) { uint4 t2 = {vv.z, vv.w, vv.x, vv.y}; vv = t2; }  // half-swap for bit-3 swz
    *(uint4*)(VsB + buf * 8192 + wswz) = vv;
  };

  const int vhalf = (ln & 8) ? 8 : 0;  // bit-3 read swizzle keyed on row bit 3

  auto compute = [&](int c, int buf) {
    const char* kb = KsB + buf * 8192;
    const char* vb = VsB + buf * 8192;
    floatx4 s[4];
    #pragma unroll
    for (int jt = 0; jt < 4; ++jt) {
      int row = jt * 16 + ln;
      half8 k0 = *(const half8*)(kb + row * 128 + ((quad ^ r7) << 4));
      half8 k1 = *(const half8*)(kb + row * 128 + (((4 + quad) ^ r7) << 4));
      floatx4 z = (floatx4){0.f, 0.f, 0.f, 0.f};
      z = __builtin_amdgcn_mfma_f32_16x16x32_f16(k0, bq0, z, 0, 0, 0);
      s[jt] = __builtin_amdgcn_mfma_f32_16x16x32_f16(k1, bq1, z, 0, 0, 0);
    }
    const int qh2 = quad >> 1, ql8 = (quad & 1) * 8;
    half4 v01[8];
    #pragma unroll
    for (int dt = 0; dt < 2; ++dt)
      #pragma unroll
      for (int jt = 0; jt < 4; ++jt)
        v01[dt * 4 + jt] = *(const half4*)(vb + (dt * 16 + ln) * 128 +
                            (((2 * jt + qh2) ^ r7) << 4) + (ql8 ^ vhalf));
    const bool full_in = (c != 0) && (c >= qw - 241) && (c <= qw + 193);
    half4 Pt[4];
    if (full_in) {
      #pragma unroll
      for (int jt = 0; jt < 4; ++jt) {
        float p0 = exp2f(fmaf(s[jt][0], SC2, -8.f));
        float p1 = exp2f(fmaf(s[jt][1], SC2, -8.f));
        float p2 = exp2f(fmaf(s[jt][2], SC2, -8.f));
        float p3 = exp2f(fmaf(s[jt][3], SC2, -8.f));
        Pt[jt] = pack4(p0, p1, p2, p3);
        l_i += (p0 + p1) + (p2 + p3);
      }
    } else {
      const int q = qw + ln;
      #pragma unroll
      for (int jt = 0; jt < 4; ++jt) {
        float pv[4];
        #pragma unroll
        for (int r = 0; r < 4; ++r) {
          int j = c + jt * 16 + quad * 4 + r;
          int dq = q - j;
          bool ok = (dq <= WIN && dq >= -WIN) && (j != 0);
          pv[r] = ok ? exp2f(fmaf(s[jt][r], SC2, -8.f)) : 0.f;
        }
        Pt[jt] = pack4(pv[0], pv[1], pv[2], pv[3]);
        l_i += (pv[0] + pv[1]) + (pv[2] + pv[3]);
      }
    }
    half4 v23[8];
    #pragma unroll
    for (int dt = 0; dt < 2; ++dt)
      #pragma unroll
      for (int jt = 0; jt < 4; ++jt)
        v23[dt * 4 + jt] = *(const half4*)(vb + ((dt + 2) * 16 + ln) * 128 +
                            (((2 * jt + qh2) ^ r7) << 4) + (ql8 ^ vhalf));
    #pragma unroll
    for (int jt = 0; jt < 4; ++jt) {
      acc[0] = __builtin_amdgcn_mfma_f32_16x16x16f16(v01[jt], Pt[jt], acc[0], 0, 0, 0);
      acc[1] = __builtin_amdgcn_mfma_f32_16x16x16f16(v01[4 + jt], Pt[jt], acc[1], 0, 0, 0);
    }
    #pragma unroll
    for (int jt = 0; jt < 4; ++jt) {
      acc[2] = __builtin_amdgcn_mfma_f32_16x16x16f16(v23[jt], Pt[jt], acc[2], 0, 0, 0);
      acc[3] = __builtin_amdgcn_mfma_f32_16x16x16f16(v23[4 + jt], Pt[jt], acc[3], 0, 0, 0);
    }
  };

  stage_load(cs);
  stage_write(0);
  __syncthreads();
  int buf = 0;
  for (int c = cs; c < ce; c += 64) {
    const bool hasnext = (c + 64 < ce);
    if (hasnext) stage_load(c + 64);
    compute(c, buf);
    if (hasnext) stage_write(buf ^ 1);
    __syncthreads();
    buf ^= 1;
  }

  // ---- window epilogue ----
  {
    float lt = l_i;
    lt += __shfl_xor(lt, 16, 64);
    lt += __shfl_xor(lt, 32, 64);
    const float inv = 1.0f / lt;
    const int q = qw + ln;
    if (q != 0) {
      #pragma unroll
      for (int dt = 0; dt < 4; ++dt) {
        ushort4 pk;
        pk.x = f2b(acc[dt][0] * inv);
        pk.y = f2b(acc[dt][1] * inv);
        pk.z = f2b(acc[dt][2] * inv);
        pk.w = f2b(acc[dt][3] * inv);
        *(ushort4*)&aout[(size_t)(b * S_LEN + q) * DM + h * DH + dt * 16 + quad * 4] = pk;
      }
    }
  }

  // ---- global q=0 row: handled by tile==0 blocks ----
  if (tile == 0) {
    float* sP = (float*)KsB;            // 2048 floats = 8KB (buf0 region)
    float* oR = (float*)VsB;            // 512 floats
    float* red = (float*)(VsB + 8192);  // 8 floats
    const int g2 = lane >> 3, e8 = lane & 7;
    const half8 q0t = *(const half8*)(Qp + e8 * 8);
    float lsum = 0.f;
    for (int it = 0; it < 32; ++it) {
      int grp = w * 32 + it;  // key j = grp*8 + g2
      const half8 kv = *(const half8*)(Kp + (size_t)(grp * 8 + g2) * DH + e8 * 8);
      float p = 0.f;
      #pragma unroll
      for (int e = 0; e < 8; ++e) p += (float)q0t[e] * (float)kv[e];
      p += __shfl_xor(p, 1, 64);
      p += __shfl_xor(p, 2, 64);
      p += __shfl_xor(p, 4, 64);
      p = exp2f(fmaf(p, SC2, -8.f));
      if (e8 == 0) sP[grp * 8 + g2] = p;
      lsum += p;  // 8x duplicated per group; divide later
    }
    #pragma unroll
    for (int off = 1; off < 64; off <<= 1) lsum += __shfl_xor(lsum, off, 64);
    if (lane == 0) red[w] = lsum;
    __syncthreads();
    const float ltot = (red[0] + red[1] + red[2] + red[3] +
                        red[4] + red[5] + red[6] + red[7]) * 0.125f;
    const int d = tid & 63, qu = tid >> 6;
    float o = 0.f;
    for (int j0 = qu * 256; j0 < qu * 256 + 256; j0 += 8) {
      half8 vv = *(const half8*)(Vp + (size_t)d * S_LEN + j0);
      #pragma unroll
      for (int e = 0; e < 8; ++e) o += sP[j0 + e] * (float)vv[e];
    }
    oR[tid] = o;
    __syncthreads();
    if (tid < 64) {
      float oo = oR[tid] + oR[tid + 64] + oR[tid + 128] + oR[tid + 192] +
                 oR[tid + 256] + oR[tid + 320] + oR[tid + 384] + oR[tid + 448];
      aout[(size_t)(b * S_LEN) * DM + h * DH + tid] = __float2bfloat16(oo / ltot);
    }
  }
}

// ---------- launch ----------
extern "C" void kernel_launch(void* const* d_in, const int* in_sizes, int n_in,
                              void* d_out, int out_size, void* d_ws, size_t ws_size,
                              hipStream_t stream) {
  const float* x  = (const float*)d_in[0];
  const float* Wq = (const float*)d_in[1];
  const float* bq = (const float*)d_in[2];
  const float* Wk = (const float*)d_in[3];
  const float* bk = (const float*)d_in[4];
  const float* Wv = (const float*)d_in[5];
  const float* bv = (const float*)d_in[6];
  const float* Wo = (const float*)d_in[7];
  const float* bo = (const float*)d_in[8];
  float* out = (float*)d_out;

  const size_t SEG = (size_t)4096 * 1024;
  bf16* xb = (bf16*)d_ws;
  bf16* wT = xb + SEG;
  fp16* Qh = (fp16*)(wT + SEG);
  fp16* Kh = Qh + SEG;
  fp16* Vt = Kh + SEG;   // [bh][d][s]
  bf16* ao = (bf16*)(Vt + SEG);

  k_prep<<<dim3(32, 32, 5), dim3(32, 8), 0, stream>>>(x, Wq, Wk, Wv, Wo, wT, (ushort4*)xb);
  k_qkv<<<dim3(192), dim3(512), 0, stream>>>(xb, wT, bq, bk, bv, Qh, Kh, Vt);
  k_attn<<<dim3(512), dim3(512), 0, stream>>>(Qh, Kh, Vt, ao);
  k_gemm<1><<<dim3(256), dim3(256), 0, stream>>>(ao, wT + (size_t)3 * 1024 * 1024, bo,
                                                 nullptr, nullptr, nullptr, nullptr, nullptr, out);
}